// Round 1
// baseline (872.381 us; speedup 1.0000x reference)
//
#include <hip/hip_runtime.h>

// Quantizer: B=8, N=4096, D=64, K=8192
// probs = softmax(sim/T) over K;  z_q = probs @ codebook
// sim = l2norm(z) @ l2norm(emb)^T, sim in [-1,1] -> no online max needed.

#define M_TOTAL 32768   // B*N
#define KCODES  8192
#define DDIM    64

typedef __attribute__((ext_vector_type(8))) short bf16x8;
typedef __attribute__((ext_vector_type(4))) short bf16x4;
typedef __attribute__((ext_vector_type(4))) float f32x4;

__device__ inline unsigned short f2bf(float x) {
  union { float f; unsigned u; } v; v.f = x;
  unsigned r = v.u + 0x7FFFu + ((v.u >> 16) & 1u);  // RNE
  return (unsigned short)(r >> 16);
}

// One wave per row: L2-normalize, emit bf16 (and optional transposed copy).
__global__ __launch_bounds__(256) void norm_rows_kernel(
    const float* __restrict__ in, unsigned short* __restrict__ out,
    unsigned short* __restrict__ outT, int nrows, int tstride) {
  int row = blockIdx.x * 4 + (threadIdx.x >> 6);
  int lane = threadIdx.x & 63;
  if (row >= nrows) return;
  size_t idx = (size_t)row * DDIM + lane;
  float x = in[idx];
  float s = x * x;
  s += __shfl_xor(s, 1);  s += __shfl_xor(s, 2);  s += __shfl_xor(s, 4);
  s += __shfl_xor(s, 8);  s += __shfl_xor(s, 16); s += __shfl_xor(s, 32);
  float scale = 1.0f / fmaxf(sqrtf(s), 1e-12f);
  unsigned short b = f2bf(x * scale);
  out[idx] = b;
  if (outT) outT[(size_t)lane * tstride + row] = b;
}

// Fused: per wave, 16 rows.  Pass A: rowsum + U = sum(e * cb) -> z_q.
// Pass B: recompute sim, write probs = e / rowsum (float4 coalesced).
__global__ __launch_bounds__(256) void fused_kernel(
    const unsigned short* __restrict__ Zn,   // [32768][64] bf16
    const unsigned short* __restrict__ Cb,   // [8192][64]  bf16
    const unsigned short* __restrict__ CbT,  // [64][8192]  bf16
    const float* __restrict__ tptr,
    float* __restrict__ probs, float* __restrict__ zq) {
  // per-wave E^T staging tile, row-padded to 56 elems (112B: 16B-aligned,
  // 2-way-bank-alias only which is free)
  __shared__ unsigned short etile[4][16 * 56];
  const int tid = threadIdx.x;
  const int w  = tid >> 6;
  const int l  = tid & 63;
  const int g  = l >> 4;     // lane group 0..3
  const int ml = l & 15;     // this lane's m (col of swapped C-layout)
  const int m_base = blockIdx.x * 64 + w * 16;
  const float T  = tptr[0];
  const float sc = 1.4426950408889634f / T;  // log2(e)/T

  // z fragments, registers for whole kernel. row = m_base+ml, d = {g*8.., 32+g*8..}
  const bf16x8* znrow = (const bf16x8*)(Zn + (size_t)(m_base + ml) * DDIM);
  const bf16x8 zn0 = znrow[g];
  const bf16x8 zn1 = znrow[4 + g];

  const f32x4 zero = {0.f, 0.f, 0.f, 0.f};
  f32x4 uacc[4] = {zero, zero, zero, zero};  // U[m][ds*16+g*4+r], m=ml
  float rs = 0.f;

  // ---------------- Pass A: rowsum + U accumulation ----------------
  for (int kc = 0; kc < KCODES; kc += 32) {
#pragma unroll
    for (int cs = 0; cs < 2; ++cs) {
      // codebook fragment: row kc+cs*16+ml, d halves
      const bf16x8* cbrow = (const bf16x8*)(Cb + (size_t)(kc + cs * 16 + ml) * DDIM);
      // sim^T tile (c x m): A=Cb(c x d), B=Zn^T(d x m)
      f32x4 acc = __builtin_amdgcn_mfma_f32_16x16x32_bf16(cbrow[g], zn0, zero, 0, 0, 0);
      acc = __builtin_amdgcn_mfma_f32_16x16x32_bf16(cbrow[4 + g], zn1, acc, 0, 0, 0);
      bf16x4 ep;
#pragma unroll
      for (int r = 0; r < 4; ++r) {
        float e = exp2f((acc[r] - 1.0f) * sc);  // exp((sim-1)/T), bounded <=1
        rs += e;
        ep[r] = (short)f2bf(e);
      }
      // lane holds E^T[c][m]: c = cs*16+g*4+r (consecutive r) -> one b64 write
      *(bf16x4*)&etile[w][ml * 56 + cs * 16 + g * 4] = ep;
    }
    asm volatile("s_waitcnt lgkmcnt(0)" ::: "memory");  // cross-lane LDS dep (same wave)
    // E^T B-fragment: B[c][m], lane: m=ml, c=g*8+j  -> ds_read_b128
    const bf16x8 ef = *(const bf16x8*)&etile[w][ml * 56 + g * 8];
    // U^T(d x m) += CbT(d x c) * E^T(c x m)
#pragma unroll
    for (int ds = 0; ds < 4; ++ds) {
      const bf16x8 ct = *(const bf16x8*)(CbT + (size_t)(ds * 16 + ml) * KCODES + kc + g * 8);
      uacc[ds] = __builtin_amdgcn_mfma_f32_16x16x32_bf16(ct, ef, uacc[ds], 0, 0, 0);
    }
  }

  // rowsum: lane partials cover c = g*4+r mod 16 -> reduce across groups
  rs += __shfl_xor(rs, 16);
  rs += __shfl_xor(rs, 32);
  const float inv = 1.0f / rs;

  // z_q = U / rowsum ; lane ml owns row m_base+ml, d = ds*16+g*4+{0..3}
  float* zqrow = zq + (size_t)(m_base + ml) * DDIM;
#pragma unroll
  for (int ds = 0; ds < 4; ++ds) {
    f32x4 v;
#pragma unroll
    for (int r = 0; r < 4; ++r) v[r] = uacc[ds][r] * inv;
    *(f32x4*)(zqrow + ds * 16 + g * 4) = v;
  }

  // ---------------- Pass B: write probs ----------------
  float* prow = probs + (size_t)(m_base + ml) * KCODES;
  for (int kc = 0; kc < KCODES; kc += 16) {
    const bf16x8* cbrow = (const bf16x8*)(Cb + (size_t)(kc + ml) * DDIM);
    f32x4 acc = __builtin_amdgcn_mfma_f32_16x16x32_bf16(cbrow[g], zn0, zero, 0, 0, 0);
    acc = __builtin_amdgcn_mfma_f32_16x16x32_bf16(cbrow[4 + g], zn1, acc, 0, 0, 0);
    f32x4 p;
#pragma unroll
    for (int r = 0; r < 4; ++r) p[r] = exp2f((acc[r] - 1.0f) * sc) * inv;
    // lane ml owns row, c = kc + g*4 + {0..3} -> coalesced float4
    *(f32x4*)(prow + kc + g * 4) = p;
  }
}

extern "C" void kernel_launch(void* const* d_in, const int* in_sizes, int n_in,
                              void* d_out, int out_size, void* d_ws, size_t ws_size,
                              hipStream_t stream) {
  const float* z    = (const float*)d_in[0];
  const float* emb  = (const float*)d_in[1];
  const float* temp = (const float*)d_in[2];

  float* probs = (float*)d_out;
  float* zq    = probs + (size_t)M_TOTAL * KCODES;  // 268435456

  unsigned short* Zn  = (unsigned short*)d_ws;              // 4 MB
  unsigned short* Cb  = Zn + (size_t)M_TOTAL * DDIM;        // 1 MB
  unsigned short* CbT = Cb + (size_t)KCODES * DDIM;         // 1 MB

  norm_rows_kernel<<<M_TOTAL / 4, 256, 0, stream>>>(z, Zn, nullptr, M_TOTAL, 0);
  norm_rows_kernel<<<KCODES / 4, 256, 0, stream>>>(emb, Cb, CbT, KCODES, KCODES);
  fused_kernel<<<M_TOTAL / 64, 256, 0, stream>>>(Zn, Cb, CbT, temp, probs, zq);
}